// Round 15
// baseline (42.040 us; speedup 1.0000x reference)
//
#include <hip/hip_runtime.h>
#include <hip/hip_bf16.h>

// RedistributionNetwork: 128 sequential tridiagonal layers on [256,1024] f32 state.
// Pipeline (3 kernels, composition tree):
//  (A) gather_compose (byte-identical to R8): one dwordx4 per (layer,row),
//      depth-4 compose -> bf16 band9[32][9][1024]  (576 KB).
//  (B) compose_9to33: pairs-of-pairs -> 16-layer operators, 33 diagonals,
//      bf16 band33[8][33][1024] (540 KB). Reads only L2-resident band9.
//  (C) propagate33: EIGHT 33-diagonal stencil steps (vs R11's 32 9-diag steps).
//      256 thr (4 waves), 4 rows/lane; halo +-16 rows = 32 shuffles + windowed
//      LDS edge patches (all compile-time register indices). The measured
//      ~500-800cy/step fixed tax (DS + barrier + LDS round trip) is paid 8x
//      instead of 32x.

#define NXL 128
#define NYP 1024
#define NB  256
#define NQ  32     // quads
#define SL  128    // rows per gather block
#define HR  136    // staged rows per layer per gather block
#define SL2 128    // rows per compose2 block
#define HR2 176    // staged rows per quad per compose2 block (24 halo each side)

struct __attribute__((packed, aligned(4))) f4u { float x, y, z, w; };

__device__ __forceinline__ float blo(unsigned u) { return __uint_as_float(u << 16); }
__device__ __forceinline__ float bhi(unsigned u) { return __uint_as_float(u & 0xffff0000u); }

// ---------------- kernel A: fused gather + compose (identical to round 8) ----------------
__global__ __launch_bounds__(256) void gather_compose(const float* __restrict__ W,
                                                      __hip_bfloat16* __restrict__ band9) {
    __shared__ float ta[4][3][HR];
    const int blk = blockIdx.x;      // 0..255
    const int q   = blk >> 3;
    const int s   = blk & 7;
    const int i0  = s * SL;
    const int tid = threadIdx.x;

#pragma unroll
    for (int g = tid; g < 4 * HR; g += 256) {
        int ly = g / HR;
        int rr = g - ly * HR;
        int i  = i0 - 4 + rr;
        float a = 0.0f, b = 0.0f, c = 0.0f;
        if ((unsigned)i < NYP) {
            size_t base = ((size_t)(4 * q + ly) << 20) + (size_t)i * (NYP + 1);
            const float* lp = W + base + ((i == 0) ? 0 : (i == NYP - 1) ? -3 : -1);
            f4u v = *reinterpret_cast<const f4u*>(lp);
            if (i == 0)            { a = 0.0f; b = v.x; c = v.y; }
            else if (i == NYP - 1) { a = v.z;  b = v.w; c = 0.0f; }
            else                   { a = v.x;  b = v.y; c = v.z; }
        }
        ta[ly][0][rr] = a;
        ta[ly][1][rr] = b;
        ta[ly][2][rr] = c;
    }
    __syncthreads();

    if (tid < SL) {
        const int i  = i0 + tid;
        const int li = tid + 4;
        float p[11], r[11];
#pragma unroll
        for (int k = 0; k < 11; ++k) { p[k] = 0.0f; r[k] = 0.0f; }
        p[4] = ta[3][0][li]; p[5] = ta[3][1][li]; p[6] = ta[3][2][li];

#pragma unroll
        for (int d = -2; d <= 2; ++d)
            r[d + 5] = fmaf(p[d + 6], ta[2][0][li + d + 1],
                       fmaf(p[d + 5], ta[2][1][li + d],
                            p[d + 4] * ta[2][2][li + d - 1]));
#pragma unroll
        for (int k = 0; k < 11; ++k) p[k] = r[k];

#pragma unroll
        for (int d = -3; d <= 3; ++d)
            r[d + 5] = fmaf(p[d + 6], ta[1][0][li + d + 1],
                       fmaf(p[d + 5], ta[1][1][li + d],
                            p[d + 4] * ta[1][2][li + d - 1]));
#pragma unroll
        for (int k = 0; k < 11; ++k) p[k] = r[k];

#pragma unroll
        for (int d = -4; d <= 4; ++d)
            r[d + 5] = fmaf(p[d + 6], ta[0][0][li + d + 1],
                       fmaf(p[d + 5], ta[0][1][li + d],
                            p[d + 4] * ta[0][2][li + d - 1]));

        __hip_bfloat16* dst = band9 + (size_t)q * 9 * NYP + i;
#pragma unroll
        for (int d = 0; d < 9; ++d)
            dst[d * NYP] = __float2bfloat16(r[d + 1]);
    }
}

// ---------------- kernel B: compose quads -> 16-layer 33-diag operators ----------------
// band33[g][d][i] = M_g[i, i+d-16], M_g = Q_{4g+3}·Q_{4g+2}·Q_{4g+1}·Q_{4g}.
// Q[k, k+o] = band9[q][o+4][k].  Row-vector sweep: p = e_i^T Q3, then p := p·Q,
// where (p·Q)[i+o] = sum_{d=-4..4} p[i+o-d] · Q[i+o-d, i+o]
//                  = sum_d p[16+o-d] · tq[ql][d+4][li+o-d].
__global__ __launch_bounds__(256) void compose_9to33(const __hip_bfloat16* __restrict__ band9,
                                                     __hip_bfloat16* __restrict__ band33) {
    __shared__ float tq[4][9][HR2];   // 25.3 KB
    const int g   = blockIdx.x >> 3;  // 0..7
    const int sl  = blockIdx.x & 7;
    const int i0  = sl * SL2;
    const int tid = threadIdx.x;

    // stage 4 quads' 9 diagonals, rows [i0-24, i0+152)
    for (int idx = tid; idx < 4 * 9 * HR2; idx += 256) {
        int ql  = idx / (9 * HR2);
        int rem = idx - ql * (9 * HR2);
        int d   = rem / HR2;
        int rr  = rem - d * HR2;
        int row = i0 - 24 + rr;
        float v = 0.0f;
        if ((unsigned)row < NYP)
            v = __bfloat162float(band9[(size_t)(4 * g + ql) * 9 * NYP + (size_t)d * NYP + row]);
        tq[ql][d][rr] = v;
    }
    __syncthreads();

    if (tid < SL2) {
        const int i  = i0 + tid;
        const int li = tid + 24;
        float p[33], r[33];
#pragma unroll
        for (int k = 0; k < 33; ++k) { p[k] = 0.0f; r[k] = 0.0f; }
        // init: row i of Q3 (support +-4)
#pragma unroll
        for (int o = -4; o <= 4; ++o)
            p[16 + o] = tq[3][o + 4][li];

        // sweep ql = 2 (support 4->8), 1 (8->12), 0 (12->16)
#pragma unroll
        for (int k = 0; k < 3; ++k) {
            const int ql = 2 - k;
            const int S  = 4 + 4 * k;      // current support of p
#pragma unroll
            for (int o = -16; o <= 16; ++o) {
                if (o < -(S + 4) || o > (S + 4)) continue;   // target support
                float acc = 0.0f;
#pragma unroll
                for (int d = -4; d <= 4; ++d) {
                    if (o - d < -S || o - d > S) continue;   // p support prune
                    acc = fmaf(p[16 + o - d], tq[ql][d + 4][li + o - d], acc);
                }
                r[16 + o] = acc;
            }
#pragma unroll
            for (int kk = 0; kk < 33; ++kk) p[kk] = r[kk];
        }

        __hip_bfloat16* dst = band33 + (size_t)g * 33 * NYP + i;
#pragma unroll
        for (int d = 0; d < 33; ++d)
            dst[(size_t)d * NYP] = __float2bfloat16(p[d]);
    }
}

// ---------------- kernel C: 8-step 33-diagonal propagation ----------------
__device__ __forceinline__ void ldsbar() {
    asm volatile("s_waitcnt lgkmcnt(0)" ::: "memory");
    __builtin_amdgcn_s_barrier();
}

// q[d] = uint2 of 4 bf16: rows r0..r0+3 of diagonal d (offset d-16)
__device__ __forceinline__ void loadq33(const __hip_bfloat16* __restrict__ band33,
                                        int g, int r0, uint2 (&q)[33]) {
    const __hip_bfloat16* base = band33 + (size_t)g * 33 * NYP + r0;
#pragma unroll
    for (int d = 0; d < 33; ++d)
        q[d] = *reinterpret_cast<const uint2*>(base + (size_t)d * NYP);
}

__device__ __forceinline__ float wv(const uint2& u, int j) {
    // j compile-time at every call site
    return (j == 0) ? blo(u.x) : (j == 1) ? bhi(u.x) : (j == 2) ? blo(u.y) : bhi(u.y);
}

// ebuf[par][B][32]: boundary B holds rows 256B-16 .. 256B+15
__device__ __forceinline__ void readwin33(const float (*e)[32], int w, int l,
                                          float (&wl)[16], float (&wr)[16]) {
    if (l < 4) {
#pragma unroll
        for (int j = 0; j < 16; ++j) wl[j] = e[w][4 * l + j];
    }
    if (l >= 60) {
#pragma unroll
        for (int j = 0; j < 16; ++j) wr[j] = e[w + 1][4 * (l - 60) + 4 + j];
    }
}

__global__ __launch_bounds__(256) void propagate33(const float* __restrict__ x,
                                                   const __hip_bfloat16* __restrict__ band33,
                                                   float* __restrict__ out) {
    __shared__ float ebuf[2][5][32];
    const int b   = blockIdx.x;
    const int tid = threadIdx.x;
    const int w   = tid >> 6;
    const int l   = tid & 63;
    const int r0  = tid << 2;    // rows r0..r0+3

    float h[4];
    {
        float4 v = *reinterpret_cast<const float4*>(x + (size_t)b * NYP + r0);
        h[0] = v.x; h[1] = v.y; h[2] = v.z; h[3] = v.w;
    }

    // zero never-published corner slots (rows <0 and >=1024), both parities
    if (tid < 16)       { ebuf[0][0][tid] = 0.0f;        ebuf[1][0][tid] = 0.0f; }
    else if (tid >= 240){ ebuf[0][4][tid - 224] = 0.0f;  ebuf[1][4][tid - 224] = 0.0f; }

    float wl[16], wr[16];
#pragma unroll
    for (int j = 0; j < 16; ++j) { wl[j] = 0.0f; wr[j] = 0.0f; }

    uint2 q[33];
    loadq33(band33, 0, r0, q);

    // prologue: publish step-0 edge rows into parity 0
    if (l < 4) {
#pragma unroll
        for (int j = 0; j < 4; ++j) ebuf[0][w][16 + 4 * l + j] = h[j];
    }
    if (l >= 60) {
#pragma unroll
        for (int j = 0; j < 4; ++j) ebuf[0][w + 1][4 * l + j - 240] = h[j];
    }
    ldsbar();
    readwin33(ebuf[0], w, l, wl, wr);

#pragma unroll 1
    for (int g = 0; g < 8; ++g) {
        // neighbor rows via shuffles: su[o-1][j] = row r0-4o+j, sd[o-1][j] = r0+4o+j
        float su[4][4], sd[4][4];
#pragma unroll
        for (int o = 1; o <= 4; ++o) {
#pragma unroll
            for (int j = 0; j < 4; ++j) {
                float u = __shfl_up(h[j], o);
                float d = __shfl_down(h[j], o);
                su[o - 1][j] = (l < o)      ? wl[16 - 4 * o + j] : u;   // compile-time wl idx
                sd[o - 1][j] = (l > 63 - o) ? wr[4 * o + j - 4]  : d;   // compile-time wr idx
            }
        }

        // n[j] = sum_{o=-16..16} wv(q[o+16], j) * row(r0+j+o); e=j+o = 4*t+s decomp
        float n[4];
#pragma unroll
        for (int j = 0; j < 4; ++j) {
            float accA = 0.0f, accB = 0.0f;   // two chains
#pragma unroll
            for (int o = -16; o <= 16; ++o) {
                const int e = j + o;
                float hv;
                if (e >= 0 && e <= 3)      hv = h[e];
                else if (e < 0) {
                    const int op = (3 - e) >> 2;        // 1..4
                    const int s  = e + 4 * op;          // 0..3
                    hv = su[op - 1][s];
                } else {
                    const int op = e >> 2;              // 1..4
                    const int s  = e & 3;
                    hv = sd[op - 1][s];
                }
                if (o < 0) accA = fmaf(wv(q[o + 16], j), hv, accA);
                else       accB = fmaf(wv(q[o + 16], j), hv, accB);
            }
            n[j] = accA + accB;
        }
#pragma unroll
        for (int j = 0; j < 4; ++j) h[j] = n[j];

        // prefetch next step's weights (same regs; consumed above already)
        loadq33(band33, (g + 1 < 8) ? g + 1 : 7, r0, q);

        // publish edge rows into the other parity, barrier, read next windows
        float (*nxt)[32] = ebuf[(g + 1) & 1];
        if (l < 4) {
#pragma unroll
            for (int j = 0; j < 4; ++j) nxt[w][16 + 4 * l + j] = h[j];
        }
        if (l >= 60) {
#pragma unroll
            for (int j = 0; j < 4; ++j) nxt[w + 1][4 * l + j - 240] = h[j];
        }
        ldsbar();
        readwin33(nxt, w, l, wl, wr);
    }

    *reinterpret_cast<float4*>(out + (size_t)b * NYP + r0) =
        make_float4(h[0], h[1], h[2], h[3]);
}

// ---------------- fallback: direct tridiag sweep from W (ws too small) ----------------
__device__ __forceinline__ float gAw(const float* __restrict__ Wl, int r) {
    return (r >= 1 && r < NYP) ? Wl[(size_t)r * NYP + (r - 1)] : 0.0f;
}
__device__ __forceinline__ float gBw(const float* __restrict__ Wl, int r) {
    return ((unsigned)r < NYP) ? Wl[(size_t)r * NYP + r] : 0.0f;
}
__device__ __forceinline__ float gCw(const float* __restrict__ Wl, int r) {
    return (r >= 0 && r < NYP - 1) ? Wl[(size_t)r * NYP + (r + 1)] : 0.0f;
}

__global__ __launch_bounds__(64) void propagate_direct(const float* __restrict__ x,
                                                       const float* __restrict__ W,
                                                       float* __restrict__ out) {
    const int b    = blockIdx.x;
    const int lane = threadIdx.x & 63;
    const int r0   = lane * 16;

    float h[16];
    const float4* xb = reinterpret_cast<const float4*>(x + (size_t)b * NYP + r0);
#pragma unroll
    for (int t = 0; t < 4; ++t) {
        float4 v = xb[t];
        h[4 * t + 0] = v.x; h[4 * t + 1] = v.y;
        h[4 * t + 2] = v.z; h[4 * t + 3] = v.w;
    }

#pragma unroll 1
    for (int ll = 0; ll < NXL; ++ll) {
        const float* Wl = W + ((size_t)ll << 20);
        float a[16], bb[16], c[16];
#pragma unroll
        for (int k = 0; k < 16; ++k) {
            int i = r0 + k;
            a[k] = gAw(Wl, i); bb[k] = gBw(Wl, i); c[k] = gCw(Wl, i);
        }
        float left  = __shfl_up(h[15], 1);
        float right = __shfl_down(h[0], 1);
        float carry = left;
        float n[16];
#pragma unroll
        for (int j = 0; j < 16; ++j) {
            float hp = (j == 15) ? right : h[j + 1];
            n[j] = fmaf(a[j], carry, fmaf(bb[j], h[j], c[j] * hp));
            carry = h[j];
        }
#pragma unroll
        for (int j = 0; j < 16; ++j) h[j] = n[j];
    }

    float4* ob = reinterpret_cast<float4*>(out + (size_t)b * NYP + r0);
#pragma unroll
    for (int t = 0; t < 4; ++t)
        ob[t] = make_float4(h[4 * t + 0], h[4 * t + 1], h[4 * t + 2], h[4 * t + 3]);
}

extern "C" void kernel_launch(void* const* d_in, const int* in_sizes, int n_in,
                              void* d_out, int out_size, void* d_ws, size_t ws_size,
                              hipStream_t stream) {
    const float* x = (const float*)d_in[0];   // [256,1024] f32
    const float* W = (const float*)d_in[1];   // [128,1024,1024] f32
    float* out = (float*)d_out;               // [256,1024] f32

    const size_t band9Bytes  = (size_t)NQ * 9 * NYP * sizeof(__hip_bfloat16);   // 576 KB
    const size_t band33Bytes = (size_t)8 * 33 * NYP * sizeof(__hip_bfloat16);   // 528 KB
    if (ws_size >= band9Bytes + band33Bytes) {
        __hip_bfloat16* band9  = (__hip_bfloat16*)d_ws;
        __hip_bfloat16* band33 = (__hip_bfloat16*)((char*)d_ws + band9Bytes);
        gather_compose<<<NQ * 8, 256, 0, stream>>>(W, band9);
        compose_9to33<<<64, 256, 0, stream>>>(band9, band33);
        propagate33<<<NB, 256, 0, stream>>>(x, band33, out);
    } else {
        propagate_direct<<<NB, 64, 0, stream>>>(x, W, out);
    }
}

// Round 16
// 27.880 us; speedup vs baseline: 1.5079x; 1.5079x over previous
//
#include <hip/hip_runtime.h>
#include <hip/hip_bf16.h>

// RedistributionNetwork: 128 sequential tridiagonal layers on [256,1024] f32 state.
// FINAL (revert to round-11 best, 27.5 us):
//  (A) gather_compose: one dwordx4 per (layer,row) -> depth-4 composed 9-diagonal
//      operators, bf16 band9[32][9][1024]. Gather is DRAM-activation-bound
//      (131072 mandatory 4KB-strided line touches; invariant across request
//      shapes R5/R6/R7) ~= 10.5 us.
//  (B) propagate9x: 32 nine-diagonal steps, 512 thr (8 waves, 2/SIMD — measured
//      optimum), 2 rows/lane, halo via 8 shuffles + parity-LDS edge patches,
//      lgkmcnt-only barrier per step (weight prefetch stays in flight) ~= 14.3 us.
// Search space exhausted: depth {1,4,8,16} x TLP {1,2,4 waves/SIMD} x {f32,bf16}
// x {split,fused} — R11 config is the measured saddle point.

#define NXL 128   // layers
#define NYP 1024  // state width
#define NB  256   // batch
#define NQ  32    // quads
#define SL  128   // output rows per compose block
#define HR  136   // gathered rows per layer per block (SL + 8 halo)

struct __attribute__((packed, aligned(4))) f4u { float x, y, z, w; };

// ---------------- kernel A: fused gather + compose ----------------
__global__ __launch_bounds__(256) void gather_compose(const float* __restrict__ W,
                                                      __hip_bfloat16* __restrict__ band9) {
    __shared__ float ta[4][3][HR];   // [layer][a,b,c][local row]
    const int blk = blockIdx.x;      // 0..255
    const int q   = blk >> 3;
    const int s   = blk & 7;
    const int i0  = s * SL;
    const int tid = threadIdx.x;

#pragma unroll
    for (int g = tid; g < 4 * HR; g += 256) {
        int ly = g / HR;
        int rr = g - ly * HR;
        int i  = i0 - 4 + rr;
        float a = 0.0f, b = 0.0f, c = 0.0f;
        if ((unsigned)i < NYP) {
            size_t base = ((size_t)(4 * q + ly) << 20) + (size_t)i * (NYP + 1);
            const float* lp = W + base + ((i == 0) ? 0 : (i == NYP - 1) ? -3 : -1);
            f4u v = *reinterpret_cast<const f4u*>(lp);
            if (i == 0)            { a = 0.0f; b = v.x; c = v.y; }
            else if (i == NYP - 1) { a = v.z;  b = v.w; c = 0.0f; }
            else                   { a = v.x;  b = v.y; c = v.z; }
        }
        ta[ly][0][rr] = a;
        ta[ly][1][rr] = b;
        ta[ly][2][rr] = c;
    }
    __syncthreads();

    if (tid < SL) {
        const int i  = i0 + tid;
        const int li = tid + 4;
        float p[11], r[11];
#pragma unroll
        for (int k = 0; k < 11; ++k) { p[k] = 0.0f; r[k] = 0.0f; }
        p[4] = ta[3][0][li]; p[5] = ta[3][1][li]; p[6] = ta[3][2][li];

#pragma unroll
        for (int d = -2; d <= 2; ++d)
            r[d + 5] = fmaf(p[d + 6], ta[2][0][li + d + 1],
                       fmaf(p[d + 5], ta[2][1][li + d],
                            p[d + 4] * ta[2][2][li + d - 1]));
#pragma unroll
        for (int k = 0; k < 11; ++k) p[k] = r[k];

#pragma unroll
        for (int d = -3; d <= 3; ++d)
            r[d + 5] = fmaf(p[d + 6], ta[1][0][li + d + 1],
                       fmaf(p[d + 5], ta[1][1][li + d],
                            p[d + 4] * ta[1][2][li + d - 1]));
#pragma unroll
        for (int k = 0; k < 11; ++k) p[k] = r[k];

#pragma unroll
        for (int d = -4; d <= 4; ++d)
            r[d + 5] = fmaf(p[d + 6], ta[0][0][li + d + 1],
                       fmaf(p[d + 5], ta[0][1][li + d],
                            p[d + 4] * ta[0][2][li + d - 1]));

        __hip_bfloat16* dst = band9 + (size_t)q * 9 * NYP + i;
#pragma unroll
        for (int d = 0; d < 9; ++d)
            dst[d * NYP] = __float2bfloat16(r[d + 1]);
    }
}

// ---------------- kernel B: 8-wave 9-diagonal propagation ----------------
__device__ __forceinline__ float blo(unsigned u) { return __uint_as_float(u << 16); }
__device__ __forceinline__ float bhi(unsigned u) { return __uint_as_float(u & 0xffff0000u); }

__device__ __forceinline__ void lds_barrier() {
    asm volatile("s_waitcnt lgkmcnt(0)" ::: "memory");
    __builtin_amdgcn_s_barrier();
}

__device__ __forceinline__ void loadW(const __hip_bfloat16* __restrict__ band9,
                                      int q, int R, unsigned (&u)[9]) {
    const __hip_bfloat16* base = band9 + (size_t)q * 9 * NYP + R;
#pragma unroll
    for (int d = 0; d < 9; ++d)
        u[d] = *reinterpret_cast<const unsigned*>(base + d * NYP);
}

__device__ __forceinline__ void read_halo(const float (*cur)[2][4], int w,
                                          float (&hL)[4], float (&hR)[4]) {
#pragma unroll
    for (int j = 0; j < 4; ++j) {
        hL[j] = (w > 0) ? cur[w - 1][1][j] : 0.0f;
        hR[j] = (w < 7) ? cur[w + 1][0][j] : 0.0f;
    }
}

__device__ __forceinline__ void stepX(float& h0, float& h1, const unsigned (&q)[9],
                                      float (&hL)[4], float (&hR)[4],
                                      float (*nxt)[2][4], int w, int l) {
    float lh0 = __shfl_up(h0, 2),   lh1 = __shfl_up(h1, 2);
    float lh2 = __shfl_up(h0, 1),   lh3 = __shfl_up(h1, 1);
    float rh0 = __shfl_down(h0, 1), rh1 = __shfl_down(h1, 1);
    float rh2 = __shfl_down(h0, 2), rh3 = __shfl_down(h1, 2);
    if (l == 0)  { lh0 = hL[0]; lh1 = hL[1]; lh2 = hL[2]; lh3 = hL[3]; }
    if (l == 1)  { lh0 = hL[2]; lh1 = hL[3]; }
    if (l == 63) { rh0 = hR[0]; rh1 = hR[1]; rh2 = hR[2]; rh3 = hR[3]; }
    if (l == 62) { rh2 = hR[0]; rh3 = hR[1]; }

    float n0 =            blo(q[0]) * lh0;
    n0 = fmaf(blo(q[1]), lh1, n0);
    n0 = fmaf(blo(q[2]), lh2, n0);
    n0 = fmaf(blo(q[3]), lh3, n0);
    n0 = fmaf(blo(q[4]), h0,  n0);
    n0 = fmaf(blo(q[5]), h1,  n0);
    n0 = fmaf(blo(q[6]), rh0, n0);
    n0 = fmaf(blo(q[7]), rh1, n0);
    n0 = fmaf(blo(q[8]), rh2, n0);
    float n1 =            bhi(q[0]) * lh1;
    n1 = fmaf(bhi(q[1]), lh2, n1);
    n1 = fmaf(bhi(q[2]), lh3, n1);
    n1 = fmaf(bhi(q[3]), h0,  n1);
    n1 = fmaf(bhi(q[4]), h1,  n1);
    n1 = fmaf(bhi(q[5]), rh0, n1);
    n1 = fmaf(bhi(q[6]), rh1, n1);
    n1 = fmaf(bhi(q[7]), rh2, n1);
    n1 = fmaf(bhi(q[8]), rh3, n1);
    h0 = n0; h1 = n1;

    if (l < 2)   { nxt[w][0][2 * l]        = h0; nxt[w][0][2 * l + 1]        = h1; }
    if (l >= 62) { nxt[w][1][2 * (l - 62)] = h0; nxt[w][1][2 * (l - 62) + 1] = h1; }
    lds_barrier();
    read_halo(nxt, w, hL, hR);
}

__global__ __launch_bounds__(512) void propagate9x(const float* __restrict__ x,
                                                   const __hip_bfloat16* __restrict__ band9,
                                                   float* __restrict__ out) {
    __shared__ float hal[2][8][2][4];
    const int b   = blockIdx.x;
    const int tid = threadIdx.x;
    const int w   = tid >> 6;
    const int l   = tid & 63;
    const int R   = tid << 1;

    float h0, h1;
    {
        float2 v = *reinterpret_cast<const float2*>(x + (size_t)b * NYP + R);
        h0 = v.x; h1 = v.y;
    }

    unsigned qa[9], qb[9];
    loadW(band9, 0, R, qa);

    if (l < 2)   { hal[0][w][0][2 * l]        = h0; hal[0][w][0][2 * l + 1]        = h1; }
    if (l >= 62) { hal[0][w][1][2 * (l - 62)] = h0; hal[0][w][1][2 * (l - 62) + 1] = h1; }
    lds_barrier();
    float hL[4], hR[4];
    read_halo(hal[0], w, hL, hR);

#pragma unroll 1
    for (int s = 0; s < NQ; s += 2) {
        loadW(band9, (s + 1 < NQ) ? s + 1 : NQ - 1, R, qb);
        stepX(h0, h1, qa, hL, hR, hal[1], w, l);
        loadW(band9, (s + 2 < NQ) ? s + 2 : NQ - 1, R, qa);
        stepX(h0, h1, qb, hL, hR, hal[0], w, l);
    }

    *reinterpret_cast<float2*>(out + (size_t)b * NYP + R) = make_float2(h0, h1);
}

// ---------------- fallback: direct tridiag sweep from W (ws too small) ----------------
__device__ __forceinline__ float gAw(const float* __restrict__ Wl, int r) {
    return (r >= 1 && r < NYP) ? Wl[(size_t)r * NYP + (r - 1)] : 0.0f;
}
__device__ __forceinline__ float gBw(const float* __restrict__ Wl, int r) {
    return ((unsigned)r < NYP) ? Wl[(size_t)r * NYP + r] : 0.0f;
}
__device__ __forceinline__ float gCw(const float* __restrict__ Wl, int r) {
    return (r >= 0 && r < NYP - 1) ? Wl[(size_t)r * NYP + (r + 1)] : 0.0f;
}

__global__ __launch_bounds__(64) void propagate_direct(const float* __restrict__ x,
                                                       const float* __restrict__ W,
                                                       float* __restrict__ out) {
    const int b    = blockIdx.x;
    const int lane = threadIdx.x & 63;
    const int r0   = lane * 16;

    float h[16];
    const float4* xb = reinterpret_cast<const float4*>(x + (size_t)b * NYP + r0);
#pragma unroll
    for (int t = 0; t < 4; ++t) {
        float4 v = xb[t];
        h[4 * t + 0] = v.x; h[4 * t + 1] = v.y;
        h[4 * t + 2] = v.z; h[4 * t + 3] = v.w;
    }

#pragma unroll 1
    for (int ll = 0; ll < NXL; ++ll) {
        const float* Wl = W + ((size_t)ll << 20);
        float a[16], bb[16], c[16];
#pragma unroll
        for (int k = 0; k < 16; ++k) {
            int i = r0 + k;
            a[k] = gAw(Wl, i); bb[k] = gBw(Wl, i); c[k] = gCw(Wl, i);
        }
        float left  = __shfl_up(h[15], 1);
        float right = __shfl_down(h[0], 1);
        float carry = left;
        float n[16];
#pragma unroll
        for (int j = 0; j < 16; ++j) {
            float hp = (j == 15) ? right : h[j + 1];
            n[j] = fmaf(a[j], carry, fmaf(bb[j], h[j], c[j] * hp));
            carry = h[j];
        }
#pragma unroll
        for (int j = 0; j < 16; ++j) h[j] = n[j];
    }

    float4* ob = reinterpret_cast<float4*>(out + (size_t)b * NYP + r0);
#pragma unroll
    for (int t = 0; t < 4; ++t)
        ob[t] = make_float4(h[4 * t + 0], h[4 * t + 1], h[4 * t + 2], h[4 * t + 3]);
}

extern "C" void kernel_launch(void* const* d_in, const int* in_sizes, int n_in,
                              void* d_out, int out_size, void* d_ws, size_t ws_size,
                              hipStream_t stream) {
    const float* x = (const float*)d_in[0];   // [256,1024] f32
    const float* W = (const float*)d_in[1];   // [128,1024,1024] f32
    float* out = (float*)d_out;               // [256,1024] f32

    const size_t band9Bytes = (size_t)NQ * 9 * NYP * sizeof(__hip_bfloat16);  // 576 KB
    if (ws_size >= band9Bytes) {
        __hip_bfloat16* band9 = (__hip_bfloat16*)d_ws;
        gather_compose<<<NQ * 8, 256, 0, stream>>>(W, band9);
        propagate9x<<<NB, 512, 0, stream>>>(x, band9, out);
    } else {
        propagate_direct<<<NB, 64, 0, stream>>>(x, W, out);
    }
}